// Round 6
// baseline (152.067 us; speedup 1.0000x reference)
//
#include <hip/hip_runtime.h>
#include <stdint.h>

#define N_DET 200
#define HW 243200
#define NP 208
#define NT 13               // 16-row tiles (208/16)
#define KSTEPS 3800         // HW/64
#define GS 256              // K-split blocks
#define SPB 15              // ceil(KSTEPS/GS)
#define TRI_TILES 91        // 13*14/2 upper-triangle tiles
#define PART_STRIDE (TRI_TILES * 256)   // f32 per block
#define LDS_STRIDE 72       // 64 + 8 pad (bf16 elems)
#define HWV (HW / 4)        // float4 per row
#define GATHER_VECS (N_DET * HWV)

typedef __attribute__((ext_vector_type(8))) short bf16x8v;
typedef __attribute__((ext_vector_type(4))) float f32x4;

__device__ __forceinline__ unsigned short f32_to_bf16(float f) {
    union { float f; uint32_t i; } v; v.f = f;
    uint32_t lsb = (v.i >> 16) & 1u;
    v.i += 0x7FFFu + lsb;          // round-to-nearest-even
    return (unsigned short)(v.i >> 16);
}

__device__ __forceinline__ void pack8(const float4& a, const float4& b, uint4& out) {
    unsigned short u[8];
    u[0] = f32_to_bf16(a.x); u[1] = f32_to_bf16(a.y);
    u[2] = f32_to_bf16(a.z); u[3] = f32_to_bf16(a.w);
    u[4] = f32_to_bf16(b.x); u[5] = f32_to_bf16(b.y);
    u[6] = f32_to_bf16(b.z); u[7] = f32_to_bf16(b.w);
    out = *(const uint4*)u;
}

// ---------------- kernel 1: K-split triangular Gram via bf16 MFMA ----------------
// LDS rows: 0..199 = bf16(masks), 200 = 1.0 (ones-row -> areas), 201..207 = 0.
// Wave wv computes tiles jt >= wv; partial stored tile-contiguous in f32
// (f32 REQUIRED: bf16 partials inject ~6e-5 gram noise -> rank swaps -> FAIL, round 5).
__global__ __launch_bounds__(832) void gram_kernel(const float* __restrict__ masks,
                                                   float* __restrict__ partial) {
    __shared__ unsigned short lds[2][NP * LDS_STRIDE];
    const int kb = blockIdx.x;
    const int s0 = kb * SPB;
    const int s1 = min(KSTEPS, s0 + SPB);

    f32x4 acc[NT];
#pragma unroll
    for (int j = 0; j < NT; ++j) acc[j] = (f32x4){0.f, 0.f, 0.f, 0.f};

    const int t = threadIdx.x;
    const int lane = t & 63, wv = t >> 6;
    const int frow = lane & 15;          // row-in-tile for A/B fragments
    const int koff = (lane >> 4) * 8;    // k-offset within 32-wide half-step
    const int srow = t >> 3;             // staging row 0..103 (then +104)
    const int scol = (t & 7) * 8;        // staging col

    const int r0 = srow, r1 = srow + 104;
    const float* src0 = masks + (size_t)r0 * HW + scol;
    const float* src1 = masks + (size_t)r1 * HW + scol;

    float4 f0a, f0b, f1a, f1b;           // prefetch regs (static names: no scratch)

    if (s0 < s1) {
        const int k0 = s0 * 64;
        if (r0 < N_DET) { f0a = *(const float4*)(src0 + k0); f0b = *(const float4*)(src0 + k0 + 4); }
        if (r1 < N_DET) { f1a = *(const float4*)(src1 + k0); f1b = *(const float4*)(src1 + k0 + 4); }
        uint4 w0, w1;
        if (r0 < N_DET) pack8(f0a, f0b, w0);
        else { const unsigned short fl = (r0 == N_DET) ? 0x3F80 : 0; unsigned short u[8];
#pragma unroll
               for (int i = 0; i < 8; ++i) u[i] = fl; w0 = *(const uint4*)u; }
        if (r1 < N_DET) pack8(f1a, f1b, w1);
        else { const unsigned short fl = (r1 == N_DET) ? 0x3F80 : 0; unsigned short u[8];
#pragma unroll
               for (int i = 0; i < 8; ++i) u[i] = fl; w1 = *(const uint4*)u; }
        *(uint4*)&lds[0][r0 * LDS_STRIDE + scol] = w0;
        *(uint4*)&lds[0][r1 * LDS_STRIDE + scol] = w1;
        __syncthreads();

        int cur = 0;
        for (int s = s0; s < s1; ++s) {
            const bool has_next = (s + 1 < s1);
            if (has_next) {
                const int kn = (s + 1) * 64;
                if (r0 < N_DET) { f0a = *(const float4*)(src0 + kn); f0b = *(const float4*)(src0 + kn + 4); }
                if (r1 < N_DET) { f1a = *(const float4*)(src1 + kn); f1b = *(const float4*)(src1 + kn + 4); }
            }

            const unsigned short* bp = &lds[cur][0];
            bf16x8v a0 = *(const bf16x8v*)&bp[(wv * 16 + frow) * LDS_STRIDE + koff];
            bf16x8v a1 = *(const bf16x8v*)&bp[(wv * 16 + frow) * LDS_STRIDE + 32 + koff];
#pragma unroll
            for (int jt = 0; jt < NT; ++jt) {
                if (jt < wv) continue;               // wave-uniform skip (triangle)
                bf16x8v b0, b1;
                if (jt == wv) { b0 = a0; b1 = a1; }
                else {
                    b0 = *(const bf16x8v*)&bp[(jt * 16 + frow) * LDS_STRIDE + koff];
                    b1 = *(const bf16x8v*)&bp[(jt * 16 + frow) * LDS_STRIDE + 32 + koff];
                }
                acc[jt] = __builtin_amdgcn_mfma_f32_16x16x32_bf16(a0, b0, acc[jt], 0, 0, 0);
                acc[jt] = __builtin_amdgcn_mfma_f32_16x16x32_bf16(a1, b1, acc[jt], 0, 0, 0);
            }

            if (has_next) {
                uint4 w0, w1;
                if (r0 < N_DET) pack8(f0a, f0b, w0);
                else { const unsigned short fl = (r0 == N_DET) ? 0x3F80 : 0; unsigned short u[8];
#pragma unroll
                       for (int i = 0; i < 8; ++i) u[i] = fl; w0 = *(const uint4*)u; }
                if (r1 < N_DET) pack8(f1a, f1b, w1);
                else { const unsigned short fl = (r1 == N_DET) ? 0x3F80 : 0; unsigned short u[8];
#pragma unroll
                       for (int i = 0; i < 8; ++i) u[i] = fl; w1 = *(const uint4*)u; }
                *(uint4*)&lds[cur ^ 1][r0 * LDS_STRIDE + scol] = w0;
                *(uint4*)&lds[cur ^ 1][r1 * LDS_STRIDE + scol] = w1;
            }
            __syncthreads();
            cur ^= 1;
        }
    }

    // store triangle tiles, tile-contiguous, f32
    float* pp = partial + (size_t)kb * PART_STRIDE;
    const int tbase = wv * 13 - (wv * (wv - 1)) / 2 - wv;   // tri(wv,jt) = tbase + jt
    const int row16 = (lane >> 4) * 4;
    const int col16 = lane & 15;
#pragma unroll
    for (int jt = 0; jt < NT; ++jt) {
        if (jt < wv) continue;
        const int tile = tbase + jt;
#pragma unroll
        for (int r = 0; r < 4; ++r)
            pp[tile * 256 + (row16 + r) * 16 + col16] = acc[jt][r];
    }
}

// ---------------- kernel 2: reduce K-split partials (f32, mirrored) ----------------
__global__ void reduce_kernel(const float* __restrict__ partial,
                              float* __restrict__ gram) {
    const int tr = blockIdx.x, tc = blockIdx.y;
    if (tc < tr) return;
    const int tile = tr * 13 - (tr * (tr - 1)) / 2 + (tc - tr);
    const int idx = threadIdx.x;
    const float* p = partial + tile * 256 + idx;
    float s = 0.f;
#pragma unroll 32
    for (int g = 0; g < GS; ++g) s += p[(size_t)g * PART_STRIDE];
    const int r = tr * 16 + (idx >> 4);
    const int c = tc * 16 + (idx & 15);
    gram[r * NP + c] = s;
    if (tr != tc) gram[c * NP + r] = s;
}

// ---------------- kernel 3: sort + matrix-NMS decay + re-sort ----------------
__global__ __launch_bounds__(1024) void nms_kernel(const float* __restrict__ scores_in,
                                                   const int* __restrict__ labels,
                                                   const float* __restrict__ gram,
                                                   float* __restrict__ out_scores,
                                                   float* __restrict__ out_labels,
                                                   float* __restrict__ out_keep) {
    __shared__ float sc[N_DET];
    __shared__ int   lab[N_DET];
    __shared__ float ar[N_DET];
    __shared__ int   order_[N_DET];
    __shared__ float sc_s[N_DET];
    __shared__ int   lab_s[N_DET];
    __shared__ float ar_s[N_DET];
    __shared__ float comp[N_DET];
    __shared__ float part[N_DET][4];
    __shared__ float nsc[N_DET];
    __shared__ int   ord2[N_DET];

    const int t = threadIdx.x;
    if (t < N_DET) {
        sc[t]  = scores_in[t];
        lab[t] = labels[t];
        ar[t]  = gram[N_DET * NP + t];   // ones-row => area
    }
    __syncthreads();

    // stable descending argsort of scores (matches jnp.argsort(-scores))
    if (t < N_DET) {
        const float si = sc[t];
        int r = 0;
        for (int j = 0; j < N_DET; ++j) {
            const float sj = sc[j];
            if (sj > si || (sj == si && j < t)) ++r;
        }
        order_[r] = t;
    }
    __syncthreads();
    if (t < N_DET) { const int o = order_[t]; sc_s[t] = sc[o]; lab_s[t] = lab[o]; ar_s[t] = ar[o]; }
    __syncthreads();

    const int j = t >> 2, sub = t & 3;
    // comp[j] = max_{i<j, same label} iou(i,j)
    if (j < N_DET) {
        float m = 0.f;
        const int oj = order_[j];
        const float aj = ar_s[j];
        const int lj = lab_s[j];
        for (int i = sub; i < j; i += 4) {
            if (lab_s[i] == lj) {
                const float g = gram[order_[i] * NP + oj];
                const float iou = g / (ar_s[i] + aj - g);
                m = fmaxf(m, iou);
            }
        }
        part[j][sub] = m;
    }
    __syncthreads();
    if (t < N_DET) comp[t] = fmaxf(fmaxf(part[t][0], part[t][1]), fmaxf(part[t][2], part[t][3]));
    __syncthreads();

    // coef[j] = min_i exp(-2*(d_ij^2 - comp_i^2))
    if (j < N_DET) {
        float mn = 1e30f;
        const int oj = order_[j];
        const float aj = ar_s[j];
        const int lj = lab_s[j];
        for (int i = sub; i < N_DET; i += 4) {
            float d = 0.f;
            if (i < j && lab_s[i] == lj) {
                const float g = gram[order_[i] * NP + oj];
                d = g / (ar_s[i] + aj - g);
            }
            const float c = comp[i];
            const float val = expf(-2.0f * (d * d - c * c));
            mn = fminf(mn, val);
        }
        part[j][sub] = mn;
    }
    __syncthreads();
    if (t < N_DET) {
        const float mn = fminf(fminf(part[t][0], part[t][1]), fminf(part[t][2], part[t][3]));
        nsc[t] = sc_s[t] * mn;
    }
    __syncthreads();

    // stable descending argsort of new scores
    if (t < N_DET) {
        const float si = nsc[t];
        int r = 0;
        for (int k = 0; k < N_DET; ++k) {
            const float sk = nsc[k];
            if (sk > si || (sk == si && k < t)) ++r;
        }
        ord2[r] = t;
    }
    __syncthreads();

    if (t < N_DET) {
        const int jj = ord2[t];
        out_scores[t] = nsc[jj];
        out_labels[t] = (float)lab_s[jj];
        out_keep[t]   = (float)order_[jj];
    }
}

// ---------------- kernel 4: grid-stride gather (f32, float4) ----------------
__global__ void gather_kernel(const float4* __restrict__ masks,
                              const float* __restrict__ keep,
                              float4* __restrict__ out_masks) {
    const int stride = gridDim.x * blockDim.x;
    for (int i = blockIdx.x * blockDim.x + threadIdx.x; i < GATHER_VECS; i += stride) {
        const int r = i / HWV;
        const int c = i - r * HWV;
        const int src = (int)keep[r];
        out_masks[i] = masks[(size_t)src * HWV + c];
    }
}

extern "C" void kernel_launch(void* const* d_in, const int* in_sizes, int n_in,
                              void* d_out, int out_size, void* d_ws, size_t ws_size,
                              hipStream_t stream) {
    const float* masks  = (const float*)d_in[0];
    const float* scores = (const float*)d_in[1];
    const int*   labels = (const int*)d_in[2];
    float* out = (float*)d_out;

    // Output layout (f32): scores[200] | labels[200] | masks[200*HW] | keep[200]
    float* out_scores = out;
    float* out_labels = out + N_DET;
    float* out_masks  = out + 2 * N_DET;
    float* out_keep   = out + 2 * N_DET + (size_t)N_DET * HW;

    // Scratch inside the not-yet-written masks output region (194.6 MB).
    // partial: GS*PART_STRIDE f32 = 23.85 MB, gram: 43264 f32. Gather overwrites last.
    float* partial = out_masks;
    float* gram    = out_masks + (size_t)GS * PART_STRIDE;

    gram_kernel<<<GS, 832, 0, stream>>>(masks, partial);
    reduce_kernel<<<dim3(13, 13), 256, 0, stream>>>(partial, gram);
    nms_kernel<<<1, 1024, 0, stream>>>(scores, labels, gram,
                                       out_scores, out_labels, out_keep);
    gather_kernel<<<2048, 256, 0, stream>>>((const float4*)masks, out_keep, (float4*)out_masks);
}

// Round 8
// 143.418 us; speedup vs baseline: 1.0603x; 1.0603x over previous
//
#include <hip/hip_runtime.h>
#include <stdint.h>

#define N_DET 200
#define HW 243200
#define NP 208
#define NT 13               // 16-row tiles (208/16)
#define KSTEPS 3800         // HW/64
#define GS 256              // K-split blocks
#define SPB 15              // ceil(KSTEPS/GS)
#define TRI_TILES 91        // 13*14/2 upper-triangle tiles
#define PART_STRIDE (TRI_TILES * 256)   // f32 per block
#define LDS_STRIDE 72       // 64 + 8 pad (bf16 elems)
#define HWV (HW / 4)        // float4 per row
#define GATHER_VECS (N_DET * HWV)

typedef __attribute__((ext_vector_type(8))) short bf16x8v;
typedef __attribute__((ext_vector_type(4))) float f32x4;

__device__ __forceinline__ unsigned short f32_to_bf16(float f) {
    union { float f; uint32_t i; } v; v.f = f;
    uint32_t lsb = (v.i >> 16) & 1u;
    v.i += 0x7FFFu + lsb;          // round-to-nearest-even
    return (unsigned short)(v.i >> 16);
}

__device__ __forceinline__ void pack8(const float4& a, const float4& b, uint4& out) {
    unsigned short u[8];
    u[0] = f32_to_bf16(a.x); u[1] = f32_to_bf16(a.y);
    u[2] = f32_to_bf16(a.z); u[3] = f32_to_bf16(a.w);
    u[4] = f32_to_bf16(b.x); u[5] = f32_to_bf16(b.y);
    u[6] = f32_to_bf16(b.z); u[7] = f32_to_bf16(b.w);
    out = *(const uint4*)u;
}

// ---------------- kernel 1: K-split triangular Gram via bf16 MFMA ----------------
// LDS rows: 0..199 = bf16(masks), 200 = 1.0 (ones-row -> areas), 201..207 = 0.
// Wave wv computes tiles jt >= wv; partial stored tile-contiguous in f32
// (f32 REQUIRED: bf16 partials inject ~6e-5 gram noise -> rank swaps -> FAIL, round 5).
__global__ __launch_bounds__(832) void gram_kernel(const float* __restrict__ masks,
                                                   float* __restrict__ partial) {
    __shared__ unsigned short lds[2][NP * LDS_STRIDE];
    const int kb = blockIdx.x;
    const int s0 = kb * SPB;
    const int s1 = min(KSTEPS, s0 + SPB);

    f32x4 acc[NT];
#pragma unroll
    for (int j = 0; j < NT; ++j) acc[j] = (f32x4){0.f, 0.f, 0.f, 0.f};

    const int t = threadIdx.x;
    const int lane = t & 63, wv = t >> 6;
    const int frow = lane & 15;          // row-in-tile for A/B fragments
    const int koff = (lane >> 4) * 8;    // k-offset within 32-wide half-step
    const int srow = t >> 3;             // staging row 0..103 (then +104)
    const int scol = (t & 7) * 8;        // staging col

    const int r0 = srow, r1 = srow + 104;
    const float* src0 = masks + (size_t)r0 * HW + scol;
    const float* src1 = masks + (size_t)r1 * HW + scol;

    float4 f0a, f0b, f1a, f1b;           // prefetch regs (static names: no scratch)

    if (s0 < s1) {
        const int k0 = s0 * 64;
        if (r0 < N_DET) { f0a = *(const float4*)(src0 + k0); f0b = *(const float4*)(src0 + k0 + 4); }
        if (r1 < N_DET) { f1a = *(const float4*)(src1 + k0); f1b = *(const float4*)(src1 + k0 + 4); }
        uint4 w0, w1;
        if (r0 < N_DET) pack8(f0a, f0b, w0);
        else { const unsigned short fl = (r0 == N_DET) ? 0x3F80 : 0; unsigned short u[8];
#pragma unroll
               for (int i = 0; i < 8; ++i) u[i] = fl; w0 = *(const uint4*)u; }
        if (r1 < N_DET) pack8(f1a, f1b, w1);
        else { const unsigned short fl = (r1 == N_DET) ? 0x3F80 : 0; unsigned short u[8];
#pragma unroll
               for (int i = 0; i < 8; ++i) u[i] = fl; w1 = *(const uint4*)u; }
        *(uint4*)&lds[0][r0 * LDS_STRIDE + scol] = w0;
        *(uint4*)&lds[0][r1 * LDS_STRIDE + scol] = w1;
        __syncthreads();

        int cur = 0;
        for (int s = s0; s < s1; ++s) {
            const bool has_next = (s + 1 < s1);
            if (has_next) {
                const int kn = (s + 1) * 64;
                if (r0 < N_DET) { f0a = *(const float4*)(src0 + kn); f0b = *(const float4*)(src0 + kn + 4); }
                if (r1 < N_DET) { f1a = *(const float4*)(src1 + kn); f1b = *(const float4*)(src1 + kn + 4); }
            }

            const unsigned short* bp = &lds[cur][0];
            bf16x8v a0 = *(const bf16x8v*)&bp[(wv * 16 + frow) * LDS_STRIDE + koff];
            bf16x8v a1 = *(const bf16x8v*)&bp[(wv * 16 + frow) * LDS_STRIDE + 32 + koff];
#pragma unroll
            for (int jt = 0; jt < NT; ++jt) {
                if (jt < wv) continue;               // wave-uniform skip (triangle)
                bf16x8v b0, b1;
                if (jt == wv) { b0 = a0; b1 = a1; }
                else {
                    b0 = *(const bf16x8v*)&bp[(jt * 16 + frow) * LDS_STRIDE + koff];
                    b1 = *(const bf16x8v*)&bp[(jt * 16 + frow) * LDS_STRIDE + 32 + koff];
                }
                acc[jt] = __builtin_amdgcn_mfma_f32_16x16x32_bf16(a0, b0, acc[jt], 0, 0, 0);
                acc[jt] = __builtin_amdgcn_mfma_f32_16x16x32_bf16(a1, b1, acc[jt], 0, 0, 0);
            }

            if (has_next) {
                uint4 w0, w1;
                if (r0 < N_DET) pack8(f0a, f0b, w0);
                else { const unsigned short fl = (r0 == N_DET) ? 0x3F80 : 0; unsigned short u[8];
#pragma unroll
                       for (int i = 0; i < 8; ++i) u[i] = fl; w0 = *(const uint4*)u; }
                if (r1 < N_DET) pack8(f1a, f1b, w1);
                else { const unsigned short fl = (r1 == N_DET) ? 0x3F80 : 0; unsigned short u[8];
#pragma unroll
                       for (int i = 0; i < 8; ++i) u[i] = fl; w1 = *(const uint4*)u; }
                *(uint4*)&lds[cur ^ 1][r0 * LDS_STRIDE + scol] = w0;
                *(uint4*)&lds[cur ^ 1][r1 * LDS_STRIDE + scol] = w1;
            }
            __syncthreads();
            cur ^= 1;
        }
    }

    // store triangle tiles, tile-contiguous, f32
    float* pp = partial + (size_t)kb * PART_STRIDE;
    const int tbase = wv * 13 - (wv * (wv - 1)) / 2 - wv;   // tri(wv,jt) = tbase + jt
    const int row16 = (lane >> 4) * 4;
    const int col16 = lane & 15;
#pragma unroll
    for (int jt = 0; jt < NT; ++jt) {
        if (jt < wv) continue;
        const int tile = tbase + jt;
#pragma unroll
        for (int r = 0; r < 4; ++r)
            pp[tile * 256 + (row16 + r) * 16 + col16] = acc[jt][r];
    }
}

// ---------------- kernel 2: reduce K-split partials (f32, mirrored) ----------------
__global__ void reduce_kernel(const float* __restrict__ partial,
                              float* __restrict__ gram) {
    const int tr = blockIdx.x, tc = blockIdx.y;
    if (tc < tr) return;
    const int tile = tr * 13 - (tr * (tr - 1)) / 2 + (tc - tr);
    const int idx = threadIdx.x;
    const float* p = partial + tile * 256 + idx;
    float s = 0.f;
#pragma unroll 32
    for (int g = 0; g < GS; ++g) s += p[(size_t)g * PART_STRIDE];
    const int r = tr * 16 + (idx >> 4);
    const int c = tc * 16 + (idx & 15);
    gram[r * NP + c] = s;
    if (tr != tc) gram[c * NP + r] = s;
}

// ---------------- kernel 3: sort + matrix-NMS decay + re-sort ----------------
// All O(N) inner loops 5-way split across threads (i = t/5, sub = t%5, 40 iters each).
// Partial combine: integer rank-sums / fmax / fmin -> bit-exact vs serial (order-safe);
// expf expression kept byte-identical (ordering noise = failure mode, round 5).
__global__ __launch_bounds__(1024) void nms_kernel(const float* __restrict__ scores_in,
                                                   const int* __restrict__ labels,
                                                   const float* __restrict__ gram,
                                                   float* __restrict__ out_scores,
                                                   float* __restrict__ out_labels,
                                                   float* __restrict__ out_keep) {
    __shared__ float sc[N_DET];
    __shared__ int   lab[N_DET];
    __shared__ float ar[N_DET];
    __shared__ int   order_[N_DET];
    __shared__ float sc_s[N_DET];
    __shared__ int   lab_s[N_DET];
    __shared__ float ar_s[N_DET];
    __shared__ float comp[N_DET];
    __shared__ float part[N_DET][5];
    __shared__ int   ipart[N_DET][5];
    __shared__ float nsc[N_DET];
    __shared__ int   ord2[N_DET];

    const int t = threadIdx.x;
    const int i5 = t / 5, s5 = t - i5 * 5;   // valid for t < 1000

    if (t < N_DET) {
        sc[t]  = scores_in[t];
        lab[t] = labels[t];
        ar[t]  = gram[N_DET * NP + t];   // ones-row => area
    }
    __syncthreads();

    // stable descending argsort of scores: 5-way partial rank counts
    if (t < 1000) {
        const float si = sc[i5];
        int r = 0;
        for (int j = s5; j < N_DET; j += 5) {
            const float sj = sc[j];
            if (sj > si || (sj == si && j < i5)) ++r;
        }
        ipart[i5][s5] = r;
    }
    __syncthreads();
    if (t < N_DET) {
        const int r = ipart[t][0] + ipart[t][1] + ipart[t][2] + ipart[t][3] + ipart[t][4];
        order_[r] = t;
    }
    __syncthreads();
    if (t < N_DET) { const int o = order_[t]; sc_s[t] = sc[o]; lab_s[t] = lab[o]; ar_s[t] = ar[o]; }
    __syncthreads();

    // comp[j] = max_{i<j, same label} iou(i,j) : 5-way
    if (t < 1000) {
        float m = 0.f;
        const int oj = order_[i5];
        const float aj = ar_s[i5];
        const int lj = lab_s[i5];
        for (int i = s5; i < i5; i += 5) {
            if (lab_s[i] == lj) {
                const float g = gram[order_[i] * NP + oj];
                const float iou = g / (ar_s[i] + aj - g);
                m = fmaxf(m, iou);
            }
        }
        part[i5][s5] = m;
    }
    __syncthreads();
    if (t < N_DET)
        comp[t] = fmaxf(fmaxf(fmaxf(part[t][0], part[t][1]), fmaxf(part[t][2], part[t][3])), part[t][4]);
    __syncthreads();

    // coef[j] = min_i exp(-2*(d_ij^2 - comp_i^2)) : 5-way
    if (t < 1000) {
        float mn = 1e30f;
        const int oj = order_[i5];
        const float aj = ar_s[i5];
        const int lj = lab_s[i5];
        for (int i = s5; i < N_DET; i += 5) {
            float d = 0.f;
            if (i < i5 && lab_s[i] == lj) {
                const float g = gram[order_[i] * NP + oj];
                d = g / (ar_s[i] + aj - g);
            }
            const float c = comp[i];
            const float val = expf(-2.0f * (d * d - c * c));
            mn = fminf(mn, val);
        }
        part[i5][s5] = mn;
    }
    __syncthreads();
    if (t < N_DET) {
        const float mn = fminf(fminf(fminf(part[t][0], part[t][1]), fminf(part[t][2], part[t][3])), part[t][4]);
        nsc[t] = sc_s[t] * mn;
    }
    __syncthreads();

    // stable descending argsort of new scores: 5-way
    if (t < 1000) {
        const float si = nsc[i5];
        int r = 0;
        for (int k = s5; k < N_DET; k += 5) {
            const float sk = nsc[k];
            if (sk > si || (sk == si && k < i5)) ++r;
        }
        ipart[i5][s5] = r;
    }
    __syncthreads();
    if (t < N_DET) {
        const int r = ipart[t][0] + ipart[t][1] + ipart[t][2] + ipart[t][3] + ipart[t][4];
        ord2[r] = t;
    }
    __syncthreads();

    if (t < N_DET) {
        const int jj = ord2[t];
        out_scores[t] = nsc[jj];
        out_labels[t] = (float)lab_s[jj];
        out_keep[t]   = (float)order_[jj];
    }
}

// ---------------- kernel 4: grid-stride gather (f32x4 ext-vector, nt stores) ----------------
// nt store keeps the 194.6 MB output stream from evicting the L3-resident masks,
// so gather reads hit Infinity Cache (masks were just streamed by gram_kernel).
// NOTE: __builtin_nontemporal_store requires a clang ext-vector type, not HIP float4.
__global__ void gather_kernel(const f32x4* __restrict__ masks,
                              const float* __restrict__ keep,
                              f32x4* __restrict__ out_masks) {
    const int stride = gridDim.x * blockDim.x;
    for (int i = blockIdx.x * blockDim.x + threadIdx.x; i < GATHER_VECS; i += stride) {
        const int r = i / HWV;
        const int c = i - r * HWV;
        const int src = (int)keep[r];
        const f32x4 v = __builtin_nontemporal_load(&masks[(size_t)src * HWV + c]);
        __builtin_nontemporal_store(v, &out_masks[i]);
    }
}

extern "C" void kernel_launch(void* const* d_in, const int* in_sizes, int n_in,
                              void* d_out, int out_size, void* d_ws, size_t ws_size,
                              hipStream_t stream) {
    const float* masks  = (const float*)d_in[0];
    const float* scores = (const float*)d_in[1];
    const int*   labels = (const int*)d_in[2];
    float* out = (float*)d_out;

    // Output layout (f32): scores[200] | labels[200] | masks[200*HW] | keep[200]
    float* out_scores = out;
    float* out_labels = out + N_DET;
    float* out_masks  = out + 2 * N_DET;
    float* out_keep   = out + 2 * N_DET + (size_t)N_DET * HW;

    // Scratch inside the not-yet-written masks output region (194.6 MB).
    // partial: GS*PART_STRIDE f32 = 23.85 MB, gram: 43264 f32. Gather overwrites last.
    float* partial = out_masks;
    float* gram    = out_masks + (size_t)GS * PART_STRIDE;

    gram_kernel<<<GS, 832, 0, stream>>>(masks, partial);
    reduce_kernel<<<dim3(13, 13), 256, 0, stream>>>(partial, gram);
    nms_kernel<<<1, 1024, 0, stream>>>(scores, labels, gram,
                                       out_scores, out_labels, out_keep);
    gather_kernel<<<2048, 256, 0, stream>>>((const f32x4*)masks, out_keep, (f32x4*)out_masks);
}

// Round 9
// 132.825 us; speedup vs baseline: 1.1449x; 1.0798x over previous
//
#include <hip/hip_runtime.h>
#include <stdint.h>

#define N_DET 200
#define HW 243200
#define NP 208
#define NT 13               // 16-row tiles (208/16)
#define KSTEPS 3800         // HW/64
#define GS 256              // K-split blocks
#define SPB 15              // ceil(KSTEPS/GS)
#define TRI_TILES 91        // 13*14/2 upper-triangle tiles
#define PART_STRIDE (TRI_TILES * 256)   // f32 per block
#define LDS_STRIDE 72       // 64 + 8 pad (bf16 elems)
#define HWV (HW / 4)        // float4 per row
#define GATHER_VECS (N_DET * HWV)

typedef __attribute__((ext_vector_type(8))) short bf16x8v;
typedef __attribute__((ext_vector_type(4))) float f32x4;

__device__ __forceinline__ unsigned short f32_to_bf16(float f) {
    union { float f; uint32_t i; } v; v.f = f;
    uint32_t lsb = (v.i >> 16) & 1u;
    v.i += 0x7FFFu + lsb;          // round-to-nearest-even
    return (unsigned short)(v.i >> 16);
}

__device__ __forceinline__ void pack8(const float4& a, const float4& b, uint4& out) {
    unsigned short u[8];
    u[0] = f32_to_bf16(a.x); u[1] = f32_to_bf16(a.y);
    u[2] = f32_to_bf16(a.z); u[3] = f32_to_bf16(a.w);
    u[4] = f32_to_bf16(b.x); u[5] = f32_to_bf16(b.y);
    u[6] = f32_to_bf16(b.z); u[7] = f32_to_bf16(b.w);
    out = *(const uint4*)u;
}

// ---------------- kernel 1: K-split triangular Gram via bf16 MFMA ----------------
// LDS rows: 0..199 = bf16(masks), 200 = 1.0 (ones-row -> areas), 201..207 = 0.
// Wave wv computes tiles jt >= wv; partial stored tile-contiguous in f32
// (f32 REQUIRED: bf16 partials inject ~6e-5 gram noise -> rank swaps -> FAIL, round 5).
__global__ __launch_bounds__(832) void gram_kernel(const float* __restrict__ masks,
                                                   float* __restrict__ partial) {
    __shared__ unsigned short lds[2][NP * LDS_STRIDE];
    const int kb = blockIdx.x;
    const int s0 = kb * SPB;
    const int s1 = min(KSTEPS, s0 + SPB);

    f32x4 acc[NT];
#pragma unroll
    for (int j = 0; j < NT; ++j) acc[j] = (f32x4){0.f, 0.f, 0.f, 0.f};

    const int t = threadIdx.x;
    const int lane = t & 63, wv = t >> 6;
    const int frow = lane & 15;          // row-in-tile for A/B fragments
    const int koff = (lane >> 4) * 8;    // k-offset within 32-wide half-step
    const int srow = t >> 3;             // staging row 0..103 (then +104)
    const int scol = (t & 7) * 8;        // staging col

    const int r0 = srow, r1 = srow + 104;
    const float* src0 = masks + (size_t)r0 * HW + scol;
    const float* src1 = masks + (size_t)r1 * HW + scol;

    float4 f0a, f0b, f1a, f1b;           // prefetch regs (static names: no scratch)

    if (s0 < s1) {
        const int k0 = s0 * 64;
        if (r0 < N_DET) { f0a = *(const float4*)(src0 + k0); f0b = *(const float4*)(src0 + k0 + 4); }
        if (r1 < N_DET) { f1a = *(const float4*)(src1 + k0); f1b = *(const float4*)(src1 + k0 + 4); }
        uint4 w0, w1;
        if (r0 < N_DET) pack8(f0a, f0b, w0);
        else { const unsigned short fl = (r0 == N_DET) ? 0x3F80 : 0; unsigned short u[8];
#pragma unroll
               for (int i = 0; i < 8; ++i) u[i] = fl; w0 = *(const uint4*)u; }
        if (r1 < N_DET) pack8(f1a, f1b, w1);
        else { const unsigned short fl = (r1 == N_DET) ? 0x3F80 : 0; unsigned short u[8];
#pragma unroll
               for (int i = 0; i < 8; ++i) u[i] = fl; w1 = *(const uint4*)u; }
        *(uint4*)&lds[0][r0 * LDS_STRIDE + scol] = w0;
        *(uint4*)&lds[0][r1 * LDS_STRIDE + scol] = w1;
        __syncthreads();

        int cur = 0;
        for (int s = s0; s < s1; ++s) {
            const bool has_next = (s + 1 < s1);
            if (has_next) {
                const int kn = (s + 1) * 64;
                if (r0 < N_DET) { f0a = *(const float4*)(src0 + kn); f0b = *(const float4*)(src0 + kn + 4); }
                if (r1 < N_DET) { f1a = *(const float4*)(src1 + kn); f1b = *(const float4*)(src1 + kn + 4); }
            }

            const unsigned short* bp = &lds[cur][0];
            bf16x8v a0 = *(const bf16x8v*)&bp[(wv * 16 + frow) * LDS_STRIDE + koff];
            bf16x8v a1 = *(const bf16x8v*)&bp[(wv * 16 + frow) * LDS_STRIDE + 32 + koff];
#pragma unroll
            for (int jt = 0; jt < NT; ++jt) {
                if (jt < wv) continue;               // wave-uniform skip (triangle)
                bf16x8v b0, b1;
                if (jt == wv) { b0 = a0; b1 = a1; }
                else {
                    b0 = *(const bf16x8v*)&bp[(jt * 16 + frow) * LDS_STRIDE + koff];
                    b1 = *(const bf16x8v*)&bp[(jt * 16 + frow) * LDS_STRIDE + 32 + koff];
                }
                acc[jt] = __builtin_amdgcn_mfma_f32_16x16x32_bf16(a0, b0, acc[jt], 0, 0, 0);
                acc[jt] = __builtin_amdgcn_mfma_f32_16x16x32_bf16(a1, b1, acc[jt], 0, 0, 0);
            }

            if (has_next) {
                uint4 w0, w1;
                if (r0 < N_DET) pack8(f0a, f0b, w0);
                else { const unsigned short fl = (r0 == N_DET) ? 0x3F80 : 0; unsigned short u[8];
#pragma unroll
                       for (int i = 0; i < 8; ++i) u[i] = fl; w0 = *(const uint4*)u; }
                if (r1 < N_DET) pack8(f1a, f1b, w1);
                else { const unsigned short fl = (r1 == N_DET) ? 0x3F80 : 0; unsigned short u[8];
#pragma unroll
                       for (int i = 0; i < 8; ++i) u[i] = fl; w1 = *(const uint4*)u; }
                *(uint4*)&lds[cur ^ 1][r0 * LDS_STRIDE + scol] = w0;
                *(uint4*)&lds[cur ^ 1][r1 * LDS_STRIDE + scol] = w1;
            }
            __syncthreads();
            cur ^= 1;
        }
    }

    // store triangle tiles, tile-contiguous, f32
    float* pp = partial + (size_t)kb * PART_STRIDE;
    const int tbase = wv * 13 - (wv * (wv - 1)) / 2 - wv;   // tri(wv,jt) = tbase + jt
    const int row16 = (lane >> 4) * 4;
    const int col16 = lane & 15;
#pragma unroll
    for (int jt = 0; jt < NT; ++jt) {
        if (jt < wv) continue;
        const int tile = tbase + jt;
#pragma unroll
        for (int r = 0; r < 4; ++r)
            pp[tile * 256 + (row16 + r) * 16 + col16] = acc[jt][r];
    }
}

// ---------------- kernel 2: reduce K-split partials (f32, mirrored) ----------------
__global__ void reduce_kernel(const float* __restrict__ partial,
                              float* __restrict__ gram) {
    const int tr = blockIdx.x, tc = blockIdx.y;
    if (tc < tr) return;
    const int tile = tr * 13 - (tr * (tr - 1)) / 2 + (tc - tr);
    const int idx = threadIdx.x;
    const float* p = partial + tile * 256 + idx;
    float s = 0.f;
#pragma unroll 32
    for (int g = 0; g < GS; ++g) s += p[(size_t)g * PART_STRIDE];
    const int r = tr * 16 + (idx >> 4);
    const int c = tc * 16 + (idx & 15);
    gram[r * NP + c] = s;
    if (tr != tc) gram[c * NP + r] = s;
}

// ---------------- kernel 3: sort + matrix-NMS decay + re-sort ----------------
// All O(N) inner loops 5-way split across threads (i = t/5, sub = t%5, 40 iters each).
// Partial combine: integer rank-sums / fmax / fmin -> bit-exact vs serial (order-safe);
// expf expression kept byte-identical (ordering noise = failure mode, round 5).
__global__ __launch_bounds__(1024) void nms_kernel(const float* __restrict__ scores_in,
                                                   const int* __restrict__ labels,
                                                   const float* __restrict__ gram,
                                                   float* __restrict__ out_scores,
                                                   float* __restrict__ out_labels,
                                                   float* __restrict__ out_keep) {
    __shared__ float sc[N_DET];
    __shared__ int   lab[N_DET];
    __shared__ float ar[N_DET];
    __shared__ int   order_[N_DET];
    __shared__ float sc_s[N_DET];
    __shared__ int   lab_s[N_DET];
    __shared__ float ar_s[N_DET];
    __shared__ float comp[N_DET];
    __shared__ float part[N_DET][5];
    __shared__ int   ipart[N_DET][5];
    __shared__ float nsc[N_DET];
    __shared__ int   ord2[N_DET];

    const int t = threadIdx.x;
    const int i5 = t / 5, s5 = t - i5 * 5;   // valid for t < 1000

    if (t < N_DET) {
        sc[t]  = scores_in[t];
        lab[t] = labels[t];
        ar[t]  = gram[N_DET * NP + t];   // ones-row => area
    }
    __syncthreads();

    // stable descending argsort of scores: 5-way partial rank counts
    if (t < 1000) {
        const float si = sc[i5];
        int r = 0;
        for (int j = s5; j < N_DET; j += 5) {
            const float sj = sc[j];
            if (sj > si || (sj == si && j < i5)) ++r;
        }
        ipart[i5][s5] = r;
    }
    __syncthreads();
    if (t < N_DET) {
        const int r = ipart[t][0] + ipart[t][1] + ipart[t][2] + ipart[t][3] + ipart[t][4];
        order_[r] = t;
    }
    __syncthreads();
    if (t < N_DET) { const int o = order_[t]; sc_s[t] = sc[o]; lab_s[t] = lab[o]; ar_s[t] = ar[o]; }
    __syncthreads();

    // comp[j] = max_{i<j, same label} iou(i,j) : 5-way
    if (t < 1000) {
        float m = 0.f;
        const int oj = order_[i5];
        const float aj = ar_s[i5];
        const int lj = lab_s[i5];
        for (int i = s5; i < i5; i += 5) {
            if (lab_s[i] == lj) {
                const float g = gram[order_[i] * NP + oj];
                const float iou = g / (ar_s[i] + aj - g);
                m = fmaxf(m, iou);
            }
        }
        part[i5][s5] = m;
    }
    __syncthreads();
    if (t < N_DET)
        comp[t] = fmaxf(fmaxf(fmaxf(part[t][0], part[t][1]), fmaxf(part[t][2], part[t][3])), part[t][4]);
    __syncthreads();

    // coef[j] = min_i exp(-2*(d_ij^2 - comp_i^2)) : 5-way
    if (t < 1000) {
        float mn = 1e30f;
        const int oj = order_[i5];
        const float aj = ar_s[i5];
        const int lj = lab_s[i5];
        for (int i = s5; i < N_DET; i += 5) {
            float d = 0.f;
            if (i < i5 && lab_s[i] == lj) {
                const float g = gram[order_[i] * NP + oj];
                d = g / (ar_s[i] + aj - g);
            }
            const float c = comp[i];
            const float val = expf(-2.0f * (d * d - c * c));
            mn = fminf(mn, val);
        }
        part[i5][s5] = mn;
    }
    __syncthreads();
    if (t < N_DET) {
        const float mn = fminf(fminf(fminf(part[t][0], part[t][1]), fminf(part[t][2], part[t][3])), part[t][4]);
        nsc[t] = sc_s[t] * mn;
    }
    __syncthreads();

    // stable descending argsort of new scores: 5-way
    if (t < 1000) {
        const float si = nsc[i5];
        int r = 0;
        for (int k = s5; k < N_DET; k += 5) {
            const float sk = nsc[k];
            if (sk > si || (sk == si && k < i5)) ++r;
        }
        ipart[i5][s5] = r;
    }
    __syncthreads();
    if (t < N_DET) {
        const int r = ipart[t][0] + ipart[t][1] + ipart[t][2] + ipart[t][3] + ipart[t][4];
        ord2[r] = t;
    }
    __syncthreads();

    if (t < N_DET) {
        const int jj = ord2[t];
        out_scores[t] = nsc[jj];
        out_labels[t] = (float)lab_s[jj];
        out_keep[t]   = (float)order_[jj];
    }
}

// ---------------- kernel 4: grid-stride gather ----------------
// Reads: PLAIN cached loads (masks are L3-resident after gram streamed them;
// round-8's nt-load likely bypassed L3 -> HBM reads -> the change under test).
// Writes: nt-store (output never re-read; don't evict the L3-resident masks).
__global__ void gather_kernel(const f32x4* __restrict__ masks,
                              const float* __restrict__ keep,
                              f32x4* __restrict__ out_masks) {
    const int stride = gridDim.x * blockDim.x;
    for (int i = blockIdx.x * blockDim.x + threadIdx.x; i < GATHER_VECS; i += stride) {
        const int r = i / HWV;
        const int c = i - r * HWV;
        const int src = (int)keep[r];
        const f32x4 v = masks[(size_t)src * HWV + c];
        __builtin_nontemporal_store(v, &out_masks[i]);
    }
}

extern "C" void kernel_launch(void* const* d_in, const int* in_sizes, int n_in,
                              void* d_out, int out_size, void* d_ws, size_t ws_size,
                              hipStream_t stream) {
    const float* masks  = (const float*)d_in[0];
    const float* scores = (const float*)d_in[1];
    const int*   labels = (const int*)d_in[2];
    float* out = (float*)d_out;

    // Output layout (f32): scores[200] | labels[200] | masks[200*HW] | keep[200]
    float* out_scores = out;
    float* out_labels = out + N_DET;
    float* out_masks  = out + 2 * N_DET;
    float* out_keep   = out + 2 * N_DET + (size_t)N_DET * HW;

    // Scratch inside the not-yet-written masks output region (194.6 MB).
    // partial: GS*PART_STRIDE f32 = 23.85 MB, gram: 43264 f32. Gather overwrites last.
    float* partial = out_masks;
    float* gram    = out_masks + (size_t)GS * PART_STRIDE;

    gram_kernel<<<GS, 832, 0, stream>>>(masks, partial);
    reduce_kernel<<<dim3(13, 13), 256, 0, stream>>>(partial, gram);
    nms_kernel<<<1, 1024, 0, stream>>>(scores, labels, gram,
                                       out_scores, out_labels, out_keep);
    gather_kernel<<<2048, 256, 0, stream>>>((const f32x4*)masks, out_keep, (f32x4*)out_masks);
}